// Round 3
// baseline (649.273 us; speedup 1.0000x reference)
//
#include <hip/hip_runtime.h>
#include <math.h>

#define H 512
#define W 512
#define PLANE (H*W)       // 262144
#define PLANE4 (PLANE/4)  // 65536

// ================= fused conv chain (one 32x32 output tile per WG) =================
// Intermediates in LDS, channels-last float4 planes. Weights/bias read straight from
// global with uniform compile-time offsets -> s_load into SGPRs (scalar cache).
// Every layer zero-forces pixels outside the image (reference zero-pads each conv).

// 1-channel (scalar plane) -> 4-channel conv
template<int SIN,int O,int SOUT>
__device__ __forceinline__ void conv_in1(
    const float* __restrict__ vb, const float* __restrict__ wgt,
    const float* __restrict__ bias, float4* __restrict__ outp,
    int tid, int gy, int gx)
{
  constexpr int NBX = SOUT/2;
  if (tid >= NBX*NBX) return;
  int by = tid/NBX, bx = tid - by*NBX;
  int y0 = by*2, x0 = bx*2;
  float a[4][4];
  #pragma unroll
  for (int co=0; co<4; ++co){
    float bv = bias[co];
    a[0][co]=bv; a[1][co]=bv; a[2][co]=bv; a[3][co]=bv;
  }
  const float* p = vb + (y0+O)*SIN + (x0+O);
  float r[4][4];
  #pragma unroll
  for (int i=0;i<4;++i)
    #pragma unroll
    for (int j=0;j<4;++j) r[i][j] = p[i*SIN+j];
  #pragma unroll
  for (int dy=0;dy<3;++dy)
    #pragma unroll
    for (int dx=0;dx<3;++dx){
      float q00=r[dy][dx], q01=r[dy][dx+1], q10=r[dy+1][dx], q11=r[dy+1][dx+1];
      #pragma unroll
      for (int co=0;co<4;++co){
        float wv = wgt[co*9 + dy*3 + dx];
        a[0][co] += q00*wv; a[1][co] += q01*wv;
        a[2][co] += q10*wv; a[3][co] += q11*wv;
      }
    }
  #pragma unroll
  for (int py=0;py<2;++py)
    #pragma unroll
    for (int px=0;px<2;++px){
      int k=py*2+px;
      bool ok = ((unsigned)(gy+y0+py)<(unsigned)H) & ((unsigned)(gx+x0+px)<(unsigned)W);
      float4 o;
      o.x = ok?fmaxf(a[k][0],0.f):0.f;
      o.y = ok?fmaxf(a[k][1],0.f):0.f;
      o.z = ok?fmaxf(a[k][2],0.f):0.f;
      o.w = ok?fmaxf(a[k][3],0.f):0.f;
      outp[(y0+py)*SOUT + (x0+px)] = o;
    }
}

// accumulate one 4-channel float4 group into a[4][4]
#define GRP4(INP, SS, OO, CIBASE, INC) { \
  const float4* p = (INP) + (y0+(OO))*(SS) + (x0+(OO)); \
  float4 r[4][4]; \
  _Pragma("unroll") \
  for (int i=0;i<4;++i){ \
    _Pragma("unroll") \
    for (int j=0;j<4;++j) r[i][j] = p[i*(SS)+j]; \
  } \
  _Pragma("unroll") \
  for (int dy=0;dy<3;++dy){ \
    _Pragma("unroll") \
    for (int dx=0;dx<3;++dx){ \
      float4 q00=r[dy][dx], q01=r[dy][dx+1], q10=r[dy+1][dx], q11=r[dy+1][dx+1]; \
      _Pragma("unroll") \
      for (int co=0;co<4;++co){ \
        const float* wb = wgt + (co*(INC)+(CIBASE))*9 + dy*3+dx; \
        float w0=wb[0], w1=wb[9], w2=wb[18], w3=wb[27]; \
        a[0][co] += q00.x*w0 + q00.y*w1 + q00.z*w2 + q00.w*w3; \
        a[1][co] += q01.x*w0 + q01.y*w1 + q01.z*w2 + q01.w*w3; \
        a[2][co] += q10.x*w0 + q10.y*w1 + q10.z*w2 + q10.w*w3; \
        a[3][co] += q11.x*w0 + q11.y*w1 + q11.z*w2 + q11.w*w3; \
      } \
    } \
  } }

// 4-or-8 channel float4 input -> 4-channel float4 output conv (relu + border mask)
template<int S1,int O1,int S2,int O2,int TWO,int SOUT,int INC>
__device__ __forceinline__ void conv44(
    const float4* __restrict__ in1, const float4* __restrict__ in2,
    const float* __restrict__ wgt, const float* __restrict__ bias,
    float4* __restrict__ outp, int tid, int gy, int gx)
{
  constexpr int NBX = SOUT/2;
  if (tid >= NBX*NBX) return;
  int by = tid/NBX, bx = tid - by*NBX;
  int y0 = by*2, x0 = bx*2;
  float a[4][4];
  #pragma unroll
  for (int co=0; co<4; ++co){
    float bv = bias[co];
    a[0][co]=bv; a[1][co]=bv; a[2][co]=bv; a[3][co]=bv;
  }
  GRP4(in1, S1, O1, 0, INC)
  if constexpr (TWO){
    GRP4(in2, S2, O2, 4, INC)
  }
  #pragma unroll
  for (int py=0;py<2;++py)
    #pragma unroll
    for (int px=0;px<2;++px){
      int k=py*2+px;
      bool ok = ((unsigned)(gy+y0+py)<(unsigned)H) & ((unsigned)(gx+x0+px)<(unsigned)W);
      float4 o;
      o.x = ok?fmaxf(a[k][0],0.f):0.f;
      o.y = ok?fmaxf(a[k][1],0.f):0.f;
      o.z = ok?fmaxf(a[k][2],0.f):0.f;
      o.w = ok?fmaxf(a[k][3],0.f):0.f;
      outp[(y0+py)*SOUT + (x0+px)] = o;
    }
}

// final conv: 8 channels -> 1, sigmoid, write 32x32 tile to global
__device__ __forceinline__ void conv_c7(
    const float4* __restrict__ x1c, const float4* __restrict__ x6,
    const float* __restrict__ wgt, const float* __restrict__ bias,
    float* __restrict__ vout, int tid)
{
  if (tid >= 256) return;
  int by = tid>>4, bx = tid&15;
  int y0 = by*2, x0 = bx*2;
  float a[4];
  float bv = bias[0];
  a[0]=bv; a[1]=bv; a[2]=bv; a[3]=bv;
#define GRPC7(INP, CIBASE) { \
  const float4* p = (INP) + y0*34 + x0; \
  float4 r[4][4]; \
  _Pragma("unroll") \
  for (int i=0;i<4;++i){ \
    _Pragma("unroll") \
    for (int j=0;j<4;++j) r[i][j] = p[i*34+j]; \
  } \
  _Pragma("unroll") \
  for (int dy=0;dy<3;++dy){ \
    _Pragma("unroll") \
    for (int dx=0;dx<3;++dx){ \
      float4 q00=r[dy][dx], q01=r[dy][dx+1], q10=r[dy+1][dx], q11=r[dy+1][dx+1]; \
      const float* wb = wgt + (CIBASE)*9 + dy*3+dx; \
      float w0=wb[0], w1=wb[9], w2=wb[18], w3=wb[27]; \
      a[0] += q00.x*w0 + q00.y*w1 + q00.z*w2 + q00.w*w3; \
      a[1] += q01.x*w0 + q01.y*w1 + q01.z*w2 + q01.w*w3; \
      a[2] += q10.x*w0 + q10.y*w1 + q10.z*w2 + q10.w*w3; \
      a[3] += q11.x*w0 + q11.y*w1 + q11.z*w2 + q11.w*w3; \
    } \
  } }
  GRPC7(x1c, 0)
  GRPC7(x6, 4)
#undef GRPC7
  #pragma unroll
  for (int py=0;py<2;++py)
    #pragma unroll
    for (int px=0;px<2;++px){
      int k=py*2+px;
      vout[(y0+py)*W + (x0+px)] = 1.f/(1.f+expf(-a[k]));
    }
}

// LDS arena: 6969 float4 = 111,504 B
// vb (scalar 46x46=2116 f = 529 f4) | SA 1936 (x1 -> x3 -> x6) | SB 1764 (x2)
// | SD 1444 (x4 -> x1c) | SE 1296 (x5)
__launch_bounds__(512, 2)
__global__ void k_megaconv(const float* __restrict__ xg,
                           const float* __restrict__ c1w, const float* __restrict__ c1b,
                           const float* __restrict__ c2w, const float* __restrict__ c2b,
                           const float* __restrict__ c3w, const float* __restrict__ c3b,
                           const float* __restrict__ c4w, const float* __restrict__ c4b,
                           const float* __restrict__ c5w, const float* __restrict__ c5b,
                           const float* __restrict__ c6w, const float* __restrict__ c6b,
                           const float* __restrict__ c7w, const float* __restrict__ c7b,
                           float* __restrict__ vr){
  __shared__ float4 arena[6969];
  int wg = blockIdx.x;                 // b*256 + ty*16 + tx
  int b  = wg >> 8;
  int t  = wg & 255;
  int ty = t >> 4, tx = t & 15;
  int gy0 = ty*32 - 7, gx0 = tx*32 - 7;
  int tid = threadIdx.x;

  float*  vb = (float*)arena;
  float4* SA = arena + 529;
  float4* SB = arena + 2465;
  float4* SD = arena + 4229;
  float4* SE = arena + 5673;

  // stage v tile from x (zero outside image)
  const float* xp = xg + (size_t)b*3*PLANE;
  for (int i=tid; i<46*46; i+=512){
    int rr = i/46, cc = i - rr*46;
    int gyy = gy0 + rr, gxx = gx0 + cc;
    float val = 0.f;
    if (((unsigned)gyy < (unsigned)H) & ((unsigned)gxx < (unsigned)W)){
      int off = gyy*W + gxx;
      val = (xp[off] + xp[PLANE+off] + xp[2*PLANE+off]) * (1.f/3.f);
    }
    vb[i] = val;
  }
  __syncthreads();

  conv_in1<46,0,44>(vb, c1w, c1b, SA, tid, gy0+1, gx0+1);                 // x1 -> SA
  __syncthreads();
  conv44<44,0, 1,0, 0, 42,4>(SA, nullptr, c2w, c2b, SB, tid, gy0+2, gx0+2); // x2 -> SB
  __syncthreads();
  conv44<42,0, 1,0, 0, 40,4>(SB, nullptr, c3w, c3b, SA, tid, gy0+3, gx0+3); // x3 -> SA
  __syncthreads();
  conv44<40,0, 1,0, 0, 38,4>(SA, nullptr, c4w, c4b, SD, tid, gy0+4, gx0+4); // x4 -> SD
  __syncthreads();
  conv44<40,1, 38,0, 1, 36,8>(SA, SD, c5w, c5b, SE, tid, gy0+5, gx0+5);     // x5 -> SE
  __syncthreads();
  conv44<42,3, 36,0, 1, 34,8>(SB, SE, c6w, c6b, SA, tid, gy0+6, gx0+6);     // x6 -> SA
  conv_in1<46,5,34>(vb, c1w, c1b, SD, tid, gy0+6, gx0+6);                   // x1 center -> SD
  __syncthreads();
  float* vout = vr + (size_t)b*PLANE + (ty*32)*W + tx*32;
  conv_c7(SD, SA, c7w, c7b, vout, tid);
}

// ---------------- subsample + m-conv(stride2) + leaky + instance norm -> src(S,B,E) ----------------
__launch_bounds__(256)
__global__ void k_mnorm(const float* __restrict__ xg, const float* __restrict__ mw,
                        const float* __restrict__ mb, const float* __restrict__ ing,
                        const float* __restrict__ inb, float* __restrict__ src){
  int bc = blockIdx.x;           // 128 = b*16+c
  int b = bc >> 4, c = bc & 15;
  int tid = threadIdx.x;         // 256 = out pixel (i*16+j)
  int i = tid >> 4, j = tid & 15;
  const float* xp = xg + (size_t)b*3*PLANE;
  float s = mb[c];
  #pragma unroll
  for (int dy=0; dy<3; ++dy){
    int ii = 2*i - 1 + dy;
    if ((unsigned)ii >= 32u) continue;
    #pragma unroll
    for (int dx=0; dx<3; ++dx){
      int jj = 2*j - 1 + dx;
      if ((unsigned)jj >= 32u) continue;
      int off = (ii*16)*W + jj*16;
      float vv = (xp[off] + xp[PLANE+off] + xp[2*PLANE+off]) * (1.f/3.f);
      s += vv * mw[c*9 + dy*3 + dx];
    }
  }
  float h = (s >= 0.f) ? s : 0.2f*s;
  __shared__ float red[256];
  red[tid] = h; __syncthreads();
  for (int off=128; off; off>>=1){ if (tid<off) red[tid]+=red[tid+off]; __syncthreads(); }
  float mu = red[0] * (1.f/256.f);
  __syncthreads();
  float d = h - mu;
  red[tid] = d*d; __syncthreads();
  for (int off=128; off; off>>=1){ if (tid<off) red[tid]+=red[tid+off]; __syncthreads(); }
  float var = red[0] * (1.f/256.f);
  float yv = d * rsqrtf(var + 1e-5f) * ing[c] + inb[c];
  src[(size_t)tid*128 + b*16 + c] = yv;   // src[s][b][e], s=tid
}

// ---------------- qkv projection ----------------
__launch_bounds__(256)
__global__ void k_qkv(const float* __restrict__ src, const float* __restrict__ aw,
                      const float* __restrict__ ab, float* __restrict__ qkv){
  int id = blockIdx.x*256 + threadIdx.x;  // 2048*48 = 98304
  int tok = id / 48, o = id % 48;
  const float* sr = src + tok*16;
  float s = ab[o];
  #pragma unroll
  for (int e=0; e<16; ++e) s += sr[e]*aw[o*16+e];
  qkv[tok*48+o] = s;
}

// ---------------- attention (per b,h block; head dim = 2) ----------------
__launch_bounds__(256)
__global__ void k_attn(const float* __restrict__ qkv, float* __restrict__ obuf){
  int b = blockIdx.x >> 3, hh = blockIdx.x & 7;  // 64 blocks
  int t = threadIdx.x;                           // s index
  __shared__ float kk0[256], kk1[256], vv0[256], vv1[256];
  int tok = t*8 + b;
  const float* qr = qkv + tok*48;
  kk0[t] = qr[16 + hh*2]; kk1[t] = qr[16 + hh*2 + 1];
  vv0[t] = qr[32 + hh*2]; vv1[t] = qr[32 + hh*2 + 1];
  float q0 = qr[hh*2], q1 = qr[hh*2 + 1];
  __syncthreads();
  const float sc = 0.70710678118654752f;  // 1/sqrt(2)
  float m = -1e30f;
  for (int u=0; u<256; ++u){
    float s = (q0*kk0[u] + q1*kk1[u]) * sc;
    m = fmaxf(m, s);
  }
  float l = 0.f, a0 = 0.f, a1 = 0.f;
  for (int u=0; u<256; ++u){
    float s = (q0*kk0[u] + q1*kk1[u]) * sc;
    float p = expf(s - m);
    l += p; a0 += p*vv0[u]; a1 += p*vv1[u];
  }
  float inv = 1.f/l;
  obuf[tok*16 + hh*2]     = a0*inv;
  obuf[tok*16 + hh*2 + 1] = a1*inv;
}

// ---------------- out-proj + residual + layernorm1 (in-place on src) ----------------
__launch_bounds__(256)
__global__ void k_oproj_ln(const float* __restrict__ obuf, const float* __restrict__ ow,
                           const float* __restrict__ obias, const float* __restrict__ g,
                           const float* __restrict__ bb, float* __restrict__ src){
  int tok = blockIdx.x*256 + threadIdx.x;  // 2048
  const float* orow = obuf + tok*16;
  float xv[16];
  #pragma unroll
  for (int e=0; e<16; ++e){
    float s = obias[e];
    #pragma unroll
    for (int f=0; f<16; ++f) s += orow[f]*ow[e*16+f];
    xv[e] = src[tok*16+e] + s;
  }
  float mu = 0.f;
  #pragma unroll
  for (int e=0; e<16; ++e) mu += xv[e];
  mu *= (1.f/16.f);
  float var = 0.f;
  #pragma unroll
  for (int e=0; e<16; ++e){ float d = xv[e]-mu; var += d*d; }
  var *= (1.f/16.f);
  float rs = rsqrtf(var + 1e-5f);
  #pragma unroll
  for (int e=0; e<16; ++e) src[tok*16+e] = (xv[e]-mu)*rs*g[e] + bb[e];
}

// ---------------- FFN + residual + layernorm2 (in-place on src) ----------------
__launch_bounds__(64)
__global__ void k_ffn_ln(float* __restrict__ src, const float* __restrict__ w1,
                         const float* __restrict__ b1, const float* __restrict__ w2,
                         const float* __restrict__ b2, const float* __restrict__ g,
                         const float* __restrict__ bb){
  int tok = blockIdx.x;     // 2048
  int tid = threadIdx.x;    // 64
  __shared__ float srow[16], h1[128], xr[16];
  if (tid < 16) srow[tid] = src[tok*16+tid];
  __syncthreads();
  for (int i = tid; i < 128; i += 64){
    float s = b1[i];
    #pragma unroll
    for (int e=0; e<16; ++e) s += srow[e]*w1[i*16+e];
    h1[i] = fmaxf(s, 0.f);
  }
  __syncthreads();
  if (tid < 16){
    float s = b2[tid];
    for (int j=0; j<128; ++j) s += h1[j]*w2[tid*128+j];
    xr[tid] = srow[tid] + s;
  }
  __syncthreads();
  if (tid < 16){
    float mu = 0.f;
    #pragma unroll
    for (int e=0; e<16; ++e) mu += xr[e];
    mu *= (1.f/16.f);
    float var = 0.f;
    #pragma unroll
    for (int e=0; e<16; ++e){ float d = xr[e]-mu; var += d*d; }
    var *= (1.f/16.f);
    src[tok*16+tid] = (xr[tid]-mu)*rsqrtf(var+1e-5f)*g[tid] + bb[tid];
  }
}

// ---------------- final 16x16 valid conv -> level -> g/bcf scalars ----------------
__launch_bounds__(256)
__global__ void k_level(const float* __restrict__ src, const float* __restrict__ fw,
                        const float* __restrict__ fb, float* __restrict__ gb){
  int b = blockIdx.x >> 1, k = blockIdx.x & 1;  // 16 blocks
  int tid = threadIdx.x;                        // s pixel
  float s = 0.f;
  #pragma unroll
  for (int c=0; c<16; ++c)
    s += src[(size_t)tid*128 + b*16 + c] * fw[(k*16+c)*256 + tid];
  __shared__ float red[256];
  red[tid] = s; __syncthreads();
  for (int off=128; off; off>>=1){ if (tid<off) red[tid]+=red[tid+off]; __syncthreads(); }
  if (tid == 0){
    float lev = 1.f/(1.f + expf(-(red[0] + fb[k])));
    gb[b*2+k] = (k==0) ? (0.1f*lev + 0.2f) : (0.04f*lev + 0.06f);
  }
}

// ---------------- final elementwise: enhance + t ----------------
__launch_bounds__(256)
__global__ void k_final(const float* __restrict__ x, const float* __restrict__ gb,
                        float* __restrict__ out){
  int id = blockIdx.x*256 + threadIdx.x;  // 524288
  int b = id >> 16, p = id & 65535;
  const float4* xr = (const float4*)(x + (size_t)(b*3+0)*PLANE);
  const float4* xg = (const float4*)(x + (size_t)(b*3+1)*PLANE);
  const float4* xb = (const float4*)(x + (size_t)(b*3+2)*PLANE);
  const float4* vrp = (const float4*)(out + 6291456 + (size_t)b*PLANE);
  float4 R = xr[p], G = xg[p], Bl = xb[p], VR = vrp[p];
  float gg = gb[b*2+0], bc = gb[b*2+1];
  float lg = log2f(gg);
  float4 er, eg, eb, tr, tg, tb;
#define COMP(SUF, RF, GF, BF, VRF) {            \
    float vv = (RF + GF + BF)/3.f;              \
    float v0 = fminf(fmaxf(vv, 1e-6f), 0.999999f); \
    float r0 = exp2f(VRF * lg);                 \
    float ev0 = exp2f(r0 * log2f(v0));          \
    float d = bc - vv;                          \
    float L = 400.f*d*d*d;                      \
    L = (L < 1e-5f) ? 1e-6f : L;                \
    float fac = (ev0 - L) / (vv + 1e-6f);       \
    er.SUF = RF*fac; eg.SUF = GF*fac; eb.SUF = BF*fac; \
    bool z = vv > 0.04f;                        \
    tr.SUF = z ? 0.f : er.SUF; tg.SUF = z ? 0.f : eg.SUF; tb.SUF = z ? 0.f : eb.SUF; }
  COMP(x, R.x, G.x, Bl.x, VR.x)
  COMP(y, R.y, G.y, Bl.y, VR.y)
  COMP(z, R.z, G.z, Bl.z, VR.z)
  COMP(w, R.w, G.w, Bl.w, VR.w)
#undef COMP
  float4* oe = (float4*)out;
  float4* ot = (float4*)(out + 8388608);
  oe[(size_t)(b*3+0)*PLANE4 + p] = er;
  oe[(size_t)(b*3+1)*PLANE4 + p] = eg;
  oe[(size_t)(b*3+2)*PLANE4 + p] = eb;
  ot[(size_t)(b*3+0)*PLANE4 + p] = tr;
  ot[(size_t)(b*3+1)*PLANE4 + p] = tg;
  ot[(size_t)(b*3+2)*PLANE4 + p] = tb;
}

extern "C" void kernel_launch(void* const* d_in, const int* in_sizes, int n_in,
                              void* d_out, int out_size, void* d_ws, size_t ws_size,
                              hipStream_t stream) {
  const float* x    = (const float*)d_in[0];
  const float* c1w  = (const float*)d_in[1];  const float* c1b = (const float*)d_in[2];
  const float* c2w  = (const float*)d_in[3];  const float* c2b = (const float*)d_in[4];
  const float* c3w  = (const float*)d_in[5];  const float* c3b = (const float*)d_in[6];
  const float* c4w  = (const float*)d_in[7];  const float* c4b = (const float*)d_in[8];
  const float* c5w  = (const float*)d_in[9];  const float* c5b = (const float*)d_in[10];
  const float* c6w  = (const float*)d_in[11]; const float* c6b = (const float*)d_in[12];
  const float* c7w  = (const float*)d_in[13]; const float* c7b = (const float*)d_in[14];
  const float* mw   = (const float*)d_in[15]; const float* mb  = (const float*)d_in[16];
  const float* ing  = (const float*)d_in[17]; const float* inb = (const float*)d_in[18];
  const float* aw   = (const float*)d_in[19]; const float* ab  = (const float*)d_in[20];
  const float* ow   = (const float*)d_in[21]; const float* ob  = (const float*)d_in[22];
  const float* l1w  = (const float*)d_in[23]; const float* l1b = (const float*)d_in[24];
  const float* l2w  = (const float*)d_in[25]; const float* l2b = (const float*)d_in[26];
  const float* n1g  = (const float*)d_in[27]; const float* n1b = (const float*)d_in[28];
  const float* n2g  = (const float*)d_in[29]; const float* n2b = (const float*)d_in[30];
  const float* fw   = (const float*)d_in[31]; const float* fb  = (const float*)d_in[32];

  float* Wp   = (float*)d_ws;
  float* src  = Wp;                    // 32,768
  float* qkv  = src + 32768;           // 98,304
  float* obuf = qkv + 98304;           // 32,768
  float* gb   = obuf+ 32768;           // 16
  float* out  = (float*)d_out;
  float* vr   = out + 6291456;         // v_r output region

  k_megaconv<<<2048,512,0,stream>>>(x, c1w,c1b, c2w,c2b, c3w,c3b, c4w,c4b,
                                    c5w,c5b, c6w,c6b, c7w,c7b, vr);
  k_mnorm<<<128,256,0,stream>>>(x, mw, mb, ing, inb, src);
  k_qkv<<<384,256,0,stream>>>(src, aw, ab, qkv);
  k_attn<<<64,256,0,stream>>>(qkv, obuf);
  k_oproj_ln<<<8,256,0,stream>>>(obuf, ow, ob, n1g, n1b, src);
  k_ffn_ln<<<2048,64,0,stream>>>(src, l1w, l1b, l2w, l2b, n2g, n2b);
  k_level<<<16,256,0,stream>>>(src, fw, fb, gb);
  k_final<<<2048,256,0,stream>>>(x, gb, out);
}

// Round 4
// 342.981 us; speedup vs baseline: 1.8930x; 1.8930x over previous
//
#include <hip/hip_runtime.h>
#include <math.h>

#define H 512
#define W 512
#define PLANE (H*W)       // 262144
#define PLANE4 (PLANE/4)  // 65536
#define PB4 262144        // float4 elems per batch plane (512*512)

// ---------- helpers ----------
__device__ __forceinline__ float ldw(const float* __restrict__ w, int i){
  // force scalar (SGPR) broadcast of a uniform weight
  return __uint_as_float((unsigned)__builtin_amdgcn_readfirstlane((int)__float_as_uint(w[i])));
}

struct R4 { float4 a,b,c,d; };
__device__ __forceinline__ R4 ldrow(const float4* __restrict__ p){
  R4 r; r.a=p[0]; r.b=p[1]; r.c=p[2]; r.d=p[3]; return r;
}
__device__ __forceinline__ float gq(const R4& r, int col, int ci){
  float4 v = (col==0)?r.a:(col==1)?r.b:(col==2)?r.c:r.d;
  return (ci==0)?v.x:(ci==1)?v.y:(ci==2)?v.z:v.w;
}
struct R4s { float a,b,c,d; };
__device__ __forceinline__ R4s ldrows(const float* __restrict__ p){
  R4s r; r.a=p[0]; r.b=p[1]; r.c=p[2]; r.d=p[3]; return r;
}
__device__ __forceinline__ float gs(const R4s& r, int col){
  return (col==0)?r.a:(col==1)?r.b:(col==2)?r.c:r.d;
}

// one dy-slice of 3x3 conv, 4-ch f4 input group, 4 co (channels-last acc)
template<int INC,int CIB,int DY>
__device__ __forceinline__ void dy_step(const R4& RL, const R4& RH,
    const float* __restrict__ wgt,
    float4& a00, float4& a01, float4& a10, float4& a11)
{
  #pragma unroll
  for (int dx=0; dx<3; ++dx){
    #pragma unroll
    for (int ci=0; ci<4; ++ci){
      const int wb = ((CIB+ci)*3+DY)*3+dx;
      float w0 = ldw(wgt, 0*INC*9 + wb);
      float w1 = ldw(wgt, 1*INC*9 + wb);
      float w2 = ldw(wgt, 2*INC*9 + wb);
      float w3 = ldw(wgt, 3*INC*9 + wb);
      float qL0 = gq(RL,dx,ci),  qL1 = gq(RL,dx+1,ci);
      float qH0 = gq(RH,dx,ci),  qH1 = gq(RH,dx+1,ci);
      a00.x += qL0*w0; a00.y += qL0*w1; a00.z += qL0*w2; a00.w += qL0*w3;
      a01.x += qL1*w0; a01.y += qL1*w1; a01.z += qL1*w2; a01.w += qL1*w3;
      a10.x += qH0*w0; a10.y += qH0*w1; a10.z += qH0*w2; a10.w += qH0*w3;
      a11.x += qH1*w0; a11.y += qH1*w1; a11.z += qH1*w2; a11.w += qH1*w3;
    }
  }
}

// full 3x3 over one 4-ch input group for a 2x2 quad (16 LDS f4 reads, row rotation)
template<int SIN,int OFF,int INC,int CIB>
__device__ __forceinline__ void acc_group(const float4* __restrict__ in,
    const float* __restrict__ wgt, int y0, int x0,
    float4& a00, float4& a01, float4& a10, float4& a11)
{
  const float4* base = in + (y0+OFF)*SIN + (x0+OFF);
  R4 r0 = ldrow(base);
  R4 r1 = ldrow(base+SIN);
  dy_step<INC,CIB,0>(r0,r1,wgt,a00,a01,a10,a11);
  R4 r2 = ldrow(base+2*SIN);
  dy_step<INC,CIB,1>(r1,r2,wgt,a00,a01,a10,a11);
  R4 r3 = ldrow(base+3*SIN);
  dy_step<INC,CIB,2>(r2,r3,wgt,a00,a01,a10,a11);
}

// scalar (1-ch) input version (c1)
template<int DY>
__device__ __forceinline__ void dy1_step(const R4s& RL, const R4s& RH,
    const float* __restrict__ wgt,
    float4& a00, float4& a01, float4& a10, float4& a11)
{
  #pragma unroll
  for (int dx=0; dx<3; ++dx){
    float w0 = ldw(wgt,  0 + DY*3+dx);
    float w1 = ldw(wgt,  9 + DY*3+dx);
    float w2 = ldw(wgt, 18 + DY*3+dx);
    float w3 = ldw(wgt, 27 + DY*3+dx);
    float qL0 = gs(RL,dx), qL1 = gs(RL,dx+1);
    float qH0 = gs(RH,dx), qH1 = gs(RH,dx+1);
    a00.x += qL0*w0; a00.y += qL0*w1; a00.z += qL0*w2; a00.w += qL0*w3;
    a01.x += qL1*w0; a01.y += qL1*w1; a01.z += qL1*w2; a01.w += qL1*w3;
    a10.x += qH0*w0; a10.y += qH0*w1; a10.z += qH0*w2; a10.w += qH0*w3;
    a11.x += qH1*w0; a11.y += qH1*w1; a11.z += qH1*w2; a11.w += qH1*w3;
  }
}
template<int SIN>
__device__ __forceinline__ void acc_group1(const float* __restrict__ in,
    const float* __restrict__ wgt, int y0, int x0,
    float4& a00, float4& a01, float4& a10, float4& a11)
{
  const float* base = in + y0*SIN + x0;
  R4s r0 = ldrows(base);
  R4s r1 = ldrows(base+SIN);
  dy1_step<0>(r0,r1,wgt,a00,a01,a10,a11);
  R4s r2 = ldrows(base+2*SIN);
  dy1_step<1>(r1,r2,wgt,a00,a01,a10,a11);
  R4s r3 = ldrows(base+3*SIN);
  dy1_step<2>(r2,r3,wgt,a00,a01,a10,a11);
}

// c7: 4-ch group -> 1 output channel (scalar acc)
template<int CIB,int DY>
__device__ __forceinline__ void dy7_step(const R4& RL, const R4& RH,
    const float* __restrict__ wgt,
    float& s00, float& s01, float& s10, float& s11)
{
  #pragma unroll
  for (int dx=0; dx<3; ++dx){
    float w0 = ldw(wgt,(CIB+0)*9+DY*3+dx);
    float w1 = ldw(wgt,(CIB+1)*9+DY*3+dx);
    float w2 = ldw(wgt,(CIB+2)*9+DY*3+dx);
    float w3 = ldw(wgt,(CIB+3)*9+DY*3+dx);
    s00 += gq(RL,dx ,0)*w0 + gq(RL,dx ,1)*w1 + gq(RL,dx ,2)*w2 + gq(RL,dx ,3)*w3;
    s01 += gq(RL,dx+1,0)*w0 + gq(RL,dx+1,1)*w1 + gq(RL,dx+1,2)*w2 + gq(RL,dx+1,3)*w3;
    s10 += gq(RH,dx ,0)*w0 + gq(RH,dx ,1)*w1 + gq(RH,dx ,2)*w2 + gq(RH,dx ,3)*w3;
    s11 += gq(RH,dx+1,0)*w0 + gq(RH,dx+1,1)*w1 + gq(RH,dx+1,2)*w2 + gq(RH,dx+1,3)*w3;
  }
}
template<int SIN,int CIB>
__device__ __forceinline__ void acc7(const float4* __restrict__ in,
    const float* __restrict__ wgt, int y0, int x0,
    float& s00, float& s01, float& s10, float& s11)
{
  const float4* base = in + y0*SIN + x0;
  R4 r0 = ldrow(base);
  R4 r1 = ldrow(base+SIN);
  dy7_step<CIB,0>(r0,r1,wgt,s00,s01,s10,s11);
  R4 r2 = ldrow(base+2*SIN);
  dy7_step<CIB,1>(r1,r2,wgt,s00,s01,s10,s11);
  R4 r3 = ldrow(base+3*SIN);
  dy7_step<CIB,2>(r2,r3,wgt,s00,s01,s10,s11);
}

// stage an SxS window of a channels-last f4 plane (0 outside image)
template<int S>
__device__ __forceinline__ void stage_plane(float4* __restrict__ dst,
    const float4* __restrict__ src, int gy0, int gx0, int tid)
{
  for (int i=tid; i<S*S; i+=512){
    int r=i/S, c=i-r*S;
    int gy=gy0+r, gx=gx0+c;
    float4 v = make_float4(0.f,0.f,0.f,0.f);
    if (((unsigned)gy<512u)&((unsigned)gx<512u)) v = src[gy*512+gx];
    dst[i] = v;
  }
}

// ================= K1: v -> x1 -> x2 -> x3 =================
__launch_bounds__(512,6)
__global__ void k_conv_a(const float* __restrict__ xg,
    const float* __restrict__ c1w, const float* __restrict__ c1b,
    const float* __restrict__ c2w, const float* __restrict__ c2b,
    const float* __restrict__ c3w, const float* __restrict__ c3b,
    float4* __restrict__ x1p, float4* __restrict__ x2p, float4* __restrict__ x3p)
{
  __shared__ float  vb[38*38];
  __shared__ float4 s1[36*36];
  __shared__ float4 s2[34*34];
  int wg=blockIdx.x, b=wg>>8, t=wg&255, ty=t>>4, tx=t&15;
  int gy0=ty*32, gx0=tx*32, tid=threadIdx.x;
  const float* xp = xg + (size_t)b*3*PLANE;
  float4* x1g = x1p + (size_t)b*PB4;
  float4* x2g = x2p + (size_t)b*PB4;
  float4* x3g = x3p + (size_t)b*PB4;

  for (int i=tid;i<38*38;i+=512){
    int r=i/38, c=i-r*38;
    int gy=gy0-3+r, gx=gx0-3+c;
    float val=0.f;
    if (((unsigned)gy<512u)&((unsigned)gx<512u)){
      int off=gy*W+gx;
      val=(xp[off]+xp[PLANE+off]+xp[2*PLANE+off])*(1.f/3.f);
    }
    vb[i]=val;
  }
  __syncthreads();

  // c1: v(38) -> x1(36), global origin gy0-2
  if (tid < 18*18){
    int qy=tid/18, qx=tid-qy*18, y0=2*qy, x0=2*qx;
    float4 a00=make_float4(ldw(c1b,0),ldw(c1b,1),ldw(c1b,2),ldw(c1b,3));
    float4 a01=a00, a10=a00, a11=a00;
    acc_group1<38>(vb, c1w, y0, x0, a00,a01,a10,a11);
#define EMIT1(A,PY,PX) { \
    int ly=y0+PY, lx=x0+PX; \
    int gy=gy0-2+ly, gx=gx0-2+lx; \
    bool ok = ((unsigned)gy<512u)&((unsigned)gx<512u); \
    float4 o; o.x=ok?fmaxf(A.x,0.f):0.f; o.y=ok?fmaxf(A.y,0.f):0.f; \
    o.z=ok?fmaxf(A.z,0.f):0.f; o.w=ok?fmaxf(A.w,0.f):0.f; \
    s1[ly*36+lx]=o; \
    if (ly>=2 && ly<34 && lx>=2 && lx<34) x1g[gy*512+gx]=o; }
    EMIT1(a00,0,0) EMIT1(a01,0,1) EMIT1(a10,1,0) EMIT1(a11,1,1)
#undef EMIT1
  }
  __syncthreads();

  // c2: x1(36) -> x2(34), global origin gy0-1
  if (tid < 17*17){
    int qy=tid/17, qx=tid-qy*17, y0=2*qy, x0=2*qx;
    float4 a00=make_float4(ldw(c2b,0),ldw(c2b,1),ldw(c2b,2),ldw(c2b,3));
    float4 a01=a00, a10=a00, a11=a00;
    acc_group<36,0,4,0>(s1, c2w, y0, x0, a00,a01,a10,a11);
#define EMIT2(A,PY,PX) { \
    int ly=y0+PY, lx=x0+PX; \
    int gy=gy0-1+ly, gx=gx0-1+lx; \
    bool ok = ((unsigned)gy<512u)&((unsigned)gx<512u); \
    float4 o; o.x=ok?fmaxf(A.x,0.f):0.f; o.y=ok?fmaxf(A.y,0.f):0.f; \
    o.z=ok?fmaxf(A.z,0.f):0.f; o.w=ok?fmaxf(A.w,0.f):0.f; \
    s2[ly*34+lx]=o; \
    if (ly>=1 && ly<33 && lx>=1 && lx<33) x2g[gy*512+gx]=o; }
    EMIT2(a00,0,0) EMIT2(a01,0,1) EMIT2(a10,1,0) EMIT2(a11,1,1)
#undef EMIT2
  }
  __syncthreads();

  // c3: x2(34) -> x3(32), global origin gy0 (all in-image)
  if (tid < 256){
    int qy=tid>>4, qx=tid&15, y0=2*qy, x0=2*qx;
    float4 a00=make_float4(ldw(c3b,0),ldw(c3b,1),ldw(c3b,2),ldw(c3b,3));
    float4 a01=a00, a10=a00, a11=a00;
    acc_group<34,0,4,0>(s2, c3w, y0, x0, a00,a01,a10,a11);
#define EMIT3(A,PY,PX) { \
    int ly=y0+PY, lx=x0+PX; \
    float4 o; o.x=fmaxf(A.x,0.f); o.y=fmaxf(A.y,0.f); \
    o.z=fmaxf(A.z,0.f); o.w=fmaxf(A.w,0.f); \
    x3g[(gy0+ly)*512 + gx0+lx]=o; }
    EMIT3(a00,0,0) EMIT3(a01,0,1) EMIT3(a10,1,0) EMIT3(a11,1,1)
#undef EMIT3
  }
}

// ================= K2: x3 -> x4 -> x5 =================
__launch_bounds__(512,6)
__global__ void k_conv_b(const float4* __restrict__ x3p,
    const float* __restrict__ c4w, const float* __restrict__ c4b,
    const float* __restrict__ c5w, const float* __restrict__ c5b,
    float4* __restrict__ x5p)
{
  __shared__ float4 s3[36*36];
  __shared__ float4 s4[34*34];
  int wg=blockIdx.x, b=wg>>8, t=wg&255, ty=t>>4, tx=t&15;
  int gy0=ty*32, gx0=tx*32, tid=threadIdx.x;
  const float4* x3g = x3p + (size_t)b*PB4;
  float4* x5g = x5p + (size_t)b*PB4;

  stage_plane<36>(s3, x3g, gy0-2, gx0-2, tid);
  __syncthreads();

  // c4: x3(36) -> x4(34), origin gy0-1 (LDS only)
  if (tid < 17*17){
    int qy=tid/17, qx=tid-qy*17, y0=2*qy, x0=2*qx;
    float4 a00=make_float4(ldw(c4b,0),ldw(c4b,1),ldw(c4b,2),ldw(c4b,3));
    float4 a01=a00, a10=a00, a11=a00;
    acc_group<36,0,4,0>(s3, c4w, y0, x0, a00,a01,a10,a11);
#define EMIT4(A,PY,PX) { \
    int ly=y0+PY, lx=x0+PX; \
    int gy=gy0-1+ly, gx=gx0-1+lx; \
    bool ok = ((unsigned)gy<512u)&((unsigned)gx<512u); \
    float4 o; o.x=ok?fmaxf(A.x,0.f):0.f; o.y=ok?fmaxf(A.y,0.f):0.f; \
    o.z=ok?fmaxf(A.z,0.f):0.f; o.w=ok?fmaxf(A.w,0.f):0.f; \
    s4[ly*34+lx]=o; }
    EMIT4(a00,0,0) EMIT4(a01,0,1) EMIT4(a10,1,0) EMIT4(a11,1,1)
#undef EMIT4
  }
  __syncthreads();

  // c5: concat(x3(36,O1), x4(34)) -> x5(32), origin gy0
  if (tid < 256){
    int qy=tid>>4, qx=tid&15, y0=2*qy, x0=2*qx;
    float4 a00=make_float4(ldw(c5b,0),ldw(c5b,1),ldw(c5b,2),ldw(c5b,3));
    float4 a01=a00, a10=a00, a11=a00;
    acc_group<36,1,8,0>(s3, c5w, y0, x0, a00,a01,a10,a11);
    acc_group<34,0,8,4>(s4, c5w, y0, x0, a00,a01,a10,a11);
#define EMIT5(A,PY,PX) { \
    int ly=y0+PY, lx=x0+PX; \
    float4 o; o.x=fmaxf(A.x,0.f); o.y=fmaxf(A.y,0.f); \
    o.z=fmaxf(A.z,0.f); o.w=fmaxf(A.w,0.f); \
    x5g[(gy0+ly)*512 + gx0+lx]=o; }
    EMIT5(a00,0,0) EMIT5(a01,0,1) EMIT5(a10,1,0) EMIT5(a11,1,1)
#undef EMIT5
  }
}

// ================= K3: x2,x5 -> x6 ; x1,x6 -> v_r =================
__launch_bounds__(512,4)
__global__ void k_conv_c(const float4* __restrict__ x1p,
    const float4* __restrict__ x2p, const float4* __restrict__ x5p,
    const float* __restrict__ c6w, const float* __restrict__ c6b,
    const float* __restrict__ c7w, const float* __restrict__ c7b,
    float* __restrict__ vr)
{
  __shared__ float4 t2[36*36];
  __shared__ float4 t5[36*36];
  __shared__ float4 t1[34*34];
  __shared__ float4 t6[34*34];
  int wg=blockIdx.x, b=wg>>8, t=wg&255, ty=t>>4, tx=t&15;
  int gy0=ty*32, gx0=tx*32, tid=threadIdx.x;

  stage_plane<36>(t2, x2p + (size_t)b*PB4, gy0-2, gx0-2, tid);
  stage_plane<36>(t5, x5p + (size_t)b*PB4, gy0-2, gx0-2, tid);
  stage_plane<34>(t1, x1p + (size_t)b*PB4, gy0-1, gx0-1, tid);
  __syncthreads();

  // c6: concat(x2(36), x5(36)) -> x6(34), origin gy0-1 (LDS only)
  if (tid < 17*17){
    int qy=tid/17, qx=tid-qy*17, y0=2*qy, x0=2*qx;
    float4 a00=make_float4(ldw(c6b,0),ldw(c6b,1),ldw(c6b,2),ldw(c6b,3));
    float4 a01=a00, a10=a00, a11=a00;
    acc_group<36,0,8,0>(t2, c6w, y0, x0, a00,a01,a10,a11);
    acc_group<36,0,8,4>(t5, c6w, y0, x0, a00,a01,a10,a11);
#define EMIT6(A,PY,PX) { \
    int ly=y0+PY, lx=x0+PX; \
    int gy=gy0-1+ly, gx=gx0-1+lx; \
    bool ok = ((unsigned)gy<512u)&((unsigned)gx<512u); \
    float4 o; o.x=ok?fmaxf(A.x,0.f):0.f; o.y=ok?fmaxf(A.y,0.f):0.f; \
    o.z=ok?fmaxf(A.z,0.f):0.f; o.w=ok?fmaxf(A.w,0.f):0.f; \
    t6[ly*34+lx]=o; }
    EMIT6(a00,0,0) EMIT6(a01,0,1) EMIT6(a10,1,0) EMIT6(a11,1,1)
#undef EMIT6
  }
  __syncthreads();

  // c7: concat(x1(34), x6(34)) -> sigmoid -> v_r(32), origin gy0
  if (tid < 256){
    int qy=tid>>4, qx=tid&15, y0=2*qy, x0=2*qx;
    float bb = ldw(c7b,0);
    float s00=bb, s01=bb, s10=bb, s11=bb;
    acc7<34,0>(t1, c7w, y0, x0, s00,s01,s10,s11);
    acc7<34,4>(t6, c7w, y0, x0, s00,s01,s10,s11);
    float* vo = vr + (size_t)b*PLANE;
    vo[(gy0+y0  )*W + gx0+x0  ] = 1.f/(1.f+expf(-s00));
    vo[(gy0+y0  )*W + gx0+x0+1] = 1.f/(1.f+expf(-s01));
    vo[(gy0+y0+1)*W + gx0+x0  ] = 1.f/(1.f+expf(-s10));
    vo[(gy0+y0+1)*W + gx0+x0+1] = 1.f/(1.f+expf(-s11));
  }
}

// ---------------- subsample + m-conv(stride2) + leaky + instance norm -> src(S,B,E) ----------------
__launch_bounds__(256)
__global__ void k_mnorm(const float* __restrict__ xg, const float* __restrict__ mw,
                        const float* __restrict__ mb, const float* __restrict__ ing,
                        const float* __restrict__ inb, float* __restrict__ src){
  int bc = blockIdx.x;           // 128 = b*16+c
  int b = bc >> 4, c = bc & 15;
  int tid = threadIdx.x;         // 256 = out pixel (i*16+j)
  int i = tid >> 4, j = tid & 15;
  const float* xp = xg + (size_t)b*3*PLANE;
  float s = mb[c];
  #pragma unroll
  for (int dy=0; dy<3; ++dy){
    int ii = 2*i - 1 + dy;
    if ((unsigned)ii >= 32u) continue;
    #pragma unroll
    for (int dx=0; dx<3; ++dx){
      int jj = 2*j - 1 + dx;
      if ((unsigned)jj >= 32u) continue;
      int off = (ii*16)*W + jj*16;
      float vv = (xp[off] + xp[PLANE+off] + xp[2*PLANE+off]) * (1.f/3.f);
      s += vv * mw[c*9 + dy*3 + dx];
    }
  }
  float h = (s >= 0.f) ? s : 0.2f*s;
  __shared__ float red[256];
  red[tid] = h; __syncthreads();
  for (int off=128; off; off>>=1){ if (tid<off) red[tid]+=red[tid+off]; __syncthreads(); }
  float mu = red[0] * (1.f/256.f);
  __syncthreads();
  float d = h - mu;
  red[tid] = d*d; __syncthreads();
  for (int off=128; off; off>>=1){ if (tid<off) red[tid]+=red[tid+off]; __syncthreads(); }
  float var = red[0] * (1.f/256.f);
  float yv = d * rsqrtf(var + 1e-5f) * ing[c] + inb[c];
  src[(size_t)tid*128 + b*16 + c] = yv;   // src[s][b][e], s=tid
}

// ---------------- qkv projection ----------------
__launch_bounds__(256)
__global__ void k_qkv(const float* __restrict__ src, const float* __restrict__ aw,
                      const float* __restrict__ ab, float* __restrict__ qkv){
  int id = blockIdx.x*256 + threadIdx.x;  // 2048*48 = 98304
  int tok = id / 48, o = id % 48;
  const float* sr = src + tok*16;
  float s = ab[o];
  #pragma unroll
  for (int e=0; e<16; ++e) s += sr[e]*aw[o*16+e];
  qkv[tok*48+o] = s;
}

// ---------------- attention (per b,h block; head dim = 2) ----------------
__launch_bounds__(256)
__global__ void k_attn(const float* __restrict__ qkv, float* __restrict__ obuf){
  int b = blockIdx.x >> 3, hh = blockIdx.x & 7;  // 64 blocks
  int t = threadIdx.x;                           // s index
  __shared__ float kk0[256], kk1[256], vv0[256], vv1[256];
  int tok = t*8 + b;
  const float* qr = qkv + tok*48;
  kk0[t] = qr[16 + hh*2]; kk1[t] = qr[16 + hh*2 + 1];
  vv0[t] = qr[32 + hh*2]; vv1[t] = qr[32 + hh*2 + 1];
  float q0 = qr[hh*2], q1 = qr[hh*2 + 1];
  __syncthreads();
  const float sc = 0.70710678118654752f;  // 1/sqrt(2)
  float m = -1e30f;
  for (int u=0; u<256; ++u){
    float s = (q0*kk0[u] + q1*kk1[u]) * sc;
    m = fmaxf(m, s);
  }
  float l = 0.f, a0 = 0.f, a1 = 0.f;
  for (int u=0; u<256; ++u){
    float s = (q0*kk0[u] + q1*kk1[u]) * sc;
    float p = expf(s - m);
    l += p; a0 += p*vv0[u]; a1 += p*vv1[u];
  }
  float inv = 1.f/l;
  obuf[tok*16 + hh*2]     = a0*inv;
  obuf[tok*16 + hh*2 + 1] = a1*inv;
}

// ---------------- out-proj + residual + layernorm1 (in-place on src) ----------------
__launch_bounds__(256)
__global__ void k_oproj_ln(const float* __restrict__ obuf, const float* __restrict__ ow,
                           const float* __restrict__ obias, const float* __restrict__ g,
                           const float* __restrict__ bb, float* __restrict__ src){
  int tok = blockIdx.x*256 + threadIdx.x;  // 2048
  const float* orow = obuf + tok*16;
  float xv[16];
  #pragma unroll
  for (int e=0; e<16; ++e){
    float s = obias[e];
    #pragma unroll
    for (int f=0; f<16; ++f) s += orow[f]*ow[e*16+f];
    xv[e] = src[tok*16+e] + s;
  }
  float mu = 0.f;
  #pragma unroll
  for (int e=0; e<16; ++e) mu += xv[e];
  mu *= (1.f/16.f);
  float var = 0.f;
  #pragma unroll
  for (int e=0; e<16; ++e){ float d = xv[e]-mu; var += d*d; }
  var *= (1.f/16.f);
  float rs = rsqrtf(var + 1e-5f);
  #pragma unroll
  for (int e=0; e<16; ++e) src[tok*16+e] = (xv[e]-mu)*rs*g[e] + bb[e];
}

// ---------------- FFN + residual + layernorm2 (in-place on src) ----------------
__launch_bounds__(64)
__global__ void k_ffn_ln(float* __restrict__ src, const float* __restrict__ w1,
                         const float* __restrict__ b1, const float* __restrict__ w2,
                         const float* __restrict__ b2, const float* __restrict__ g,
                         const float* __restrict__ bb){
  int tok = blockIdx.x;     // 2048
  int tid = threadIdx.x;    // 64
  __shared__ float srow[16], h1[128], xr[16];
  if (tid < 16) srow[tid] = src[tok*16+tid];
  __syncthreads();
  for (int i = tid; i < 128; i += 64){
    float s = b1[i];
    #pragma unroll
    for (int e=0; e<16; ++e) s += srow[e]*w1[i*16+e];
    h1[i] = fmaxf(s, 0.f);
  }
  __syncthreads();
  if (tid < 16){
    float s = b2[tid];
    for (int j=0; j<128; ++j) s += h1[j]*w2[tid*128+j];
    xr[tid] = srow[tid] + s;
  }
  __syncthreads();
  if (tid < 16){
    float mu = 0.f;
    #pragma unroll
    for (int e=0; e<16; ++e) mu += xr[e];
    mu *= (1.f/16.f);
    float var = 0.f;
    #pragma unroll
    for (int e=0; e<16; ++e){ float d = xr[e]-mu; var += d*d; }
    var *= (1.f/16.f);
    src[tok*16+tid] = (xr[tid]-mu)*rsqrtf(var+1e-5f)*g[tid] + bb[tid];
  }
}

// ---------------- final 16x16 valid conv -> level -> g/bcf scalars ----------------
__launch_bounds__(256)
__global__ void k_level(const float* __restrict__ src, const float* __restrict__ fw,
                        const float* __restrict__ fb, float* __restrict__ gb){
  int b = blockIdx.x >> 1, k = blockIdx.x & 1;  // 16 blocks
  int tid = threadIdx.x;                        // s pixel
  float s = 0.f;
  #pragma unroll
  for (int c=0; c<16; ++c)
    s += src[(size_t)tid*128 + b*16 + c] * fw[(k*16+c)*256 + tid];
  __shared__ float red[256];
  red[tid] = s; __syncthreads();
  for (int off=128; off; off>>=1){ if (tid<off) red[tid]+=red[tid+off]; __syncthreads(); }
  if (tid == 0){
    float lev = 1.f/(1.f + expf(-(red[0] + fb[k])));
    gb[b*2+k] = (k==0) ? (0.1f*lev + 0.2f) : (0.04f*lev + 0.06f);
  }
}

// ---------------- final elementwise: enhance + t ----------------
__launch_bounds__(256)
__global__ void k_final(const float* __restrict__ x, const float* __restrict__ gb,
                        float* __restrict__ out){
  int id = blockIdx.x*256 + threadIdx.x;  // 524288
  int b = id >> 16, p = id & 65535;
  const float4* xr = (const float4*)(x + (size_t)(b*3+0)*PLANE);
  const float4* xg = (const float4*)(x + (size_t)(b*3+1)*PLANE);
  const float4* xb = (const float4*)(x + (size_t)(b*3+2)*PLANE);
  const float4* vrp = (const float4*)(out + 6291456 + (size_t)b*PLANE);
  float4 R = xr[p], G = xg[p], Bl = xb[p], VR = vrp[p];
  float gg = gb[b*2+0], bc = gb[b*2+1];
  float lg = log2f(gg);
  float4 er, eg, eb, tr, tg, tb;
#define COMP(SUF, RF, GF, BF, VRF) {            \
    float vv = (RF + GF + BF)/3.f;              \
    float v0 = fminf(fmaxf(vv, 1e-6f), 0.999999f); \
    float r0 = exp2f(VRF * lg);                 \
    float ev0 = exp2f(r0 * log2f(v0));          \
    float d = bc - vv;                          \
    float L = 400.f*d*d*d;                      \
    L = (L < 1e-5f) ? 1e-6f : L;                \
    float fac = (ev0 - L) / (vv + 1e-6f);       \
    er.SUF = RF*fac; eg.SUF = GF*fac; eb.SUF = BF*fac; \
    bool z = vv > 0.04f;                        \
    tr.SUF = z ? 0.f : er.SUF; tg.SUF = z ? 0.f : eg.SUF; tb.SUF = z ? 0.f : eb.SUF; }
  COMP(x, R.x, G.x, Bl.x, VR.x)
  COMP(y, R.y, G.y, Bl.y, VR.y)
  COMP(z, R.z, G.z, Bl.z, VR.z)
  COMP(w, R.w, G.w, Bl.w, VR.w)
#undef COMP
  float4* oe = (float4*)out;
  float4* ot = (float4*)(out + 8388608);
  oe[(size_t)(b*3+0)*PLANE4 + p] = er;
  oe[(size_t)(b*3+1)*PLANE4 + p] = eg;
  oe[(size_t)(b*3+2)*PLANE4 + p] = eb;
  ot[(size_t)(b*3+0)*PLANE4 + p] = tr;
  ot[(size_t)(b*3+1)*PLANE4 + p] = tg;
  ot[(size_t)(b*3+2)*PLANE4 + p] = tb;
}

extern "C" void kernel_launch(void* const* d_in, const int* in_sizes, int n_in,
                              void* d_out, int out_size, void* d_ws, size_t ws_size,
                              hipStream_t stream) {
  const float* x    = (const float*)d_in[0];
  const float* c1w  = (const float*)d_in[1];  const float* c1b = (const float*)d_in[2];
  const float* c2w  = (const float*)d_in[3];  const float* c2b = (const float*)d_in[4];
  const float* c3w  = (const float*)d_in[5];  const float* c3b = (const float*)d_in[6];
  const float* c4w  = (const float*)d_in[7];  const float* c4b = (const float*)d_in[8];
  const float* c5w  = (const float*)d_in[9];  const float* c5b = (const float*)d_in[10];
  const float* c6w  = (const float*)d_in[11]; const float* c6b = (const float*)d_in[12];
  const float* c7w  = (const float*)d_in[13]; const float* c7b = (const float*)d_in[14];
  const float* mw   = (const float*)d_in[15]; const float* mb  = (const float*)d_in[16];
  const float* ing  = (const float*)d_in[17]; const float* inb = (const float*)d_in[18];
  const float* aw   = (const float*)d_in[19]; const float* ab  = (const float*)d_in[20];
  const float* ow   = (const float*)d_in[21]; const float* ob  = (const float*)d_in[22];
  const float* l1w  = (const float*)d_in[23]; const float* l1b = (const float*)d_in[24];
  const float* l2w  = (const float*)d_in[25]; const float* l2b = (const float*)d_in[26];
  const float* n1g  = (const float*)d_in[27]; const float* n1b = (const float*)d_in[28];
  const float* n2g  = (const float*)d_in[29]; const float* n2b = (const float*)d_in[30];
  const float* fw   = (const float*)d_in[31]; const float* fb  = (const float*)d_in[32];

  float4* ws4 = (float4*)d_ws;
  float4* x1p = ws4;                 // 8 batches x 262144 f4 = 33.5 MB
  float4* x2p = x1p + 8*PB4;
  float4* x3p = x2p + 8*PB4;
  float4* x5p = x3p + 8*PB4;
  float* smallws = (float*)(x5p + 8*PB4);
  float* src  = smallws;             // 32,768
  float* qkv  = src + 32768;         // 98,304
  float* obuf = qkv + 98304;         // 32,768
  float* gb   = obuf+ 32768;         // 16
  float* out  = (float*)d_out;
  float* vr   = out + 6291456;       // v_r output region

  k_conv_a<<<2048,512,0,stream>>>(x, c1w,c1b, c2w,c2b, c3w,c3b, x1p, x2p, x3p);
  k_conv_b<<<2048,512,0,stream>>>(x3p, c4w,c4b, c5w,c5b, x5p);
  k_conv_c<<<2048,512,0,stream>>>(x1p, x2p, x5p, c6w,c6b, c7w,c7b, vr);
  k_mnorm<<<128,256,0,stream>>>(x, mw, mb, ing, inb, src);
  k_qkv<<<384,256,0,stream>>>(src, aw, ab, qkv);
  k_attn<<<64,256,0,stream>>>(qkv, obuf);
  k_oproj_ln<<<8,256,0,stream>>>(obuf, ow, ob, n1g, n1b, src);
  k_ffn_ln<<<2048,64,0,stream>>>(src, l1w, l1b, l2w, l2b, n2g, n2b);
  k_level<<<16,256,0,stream>>>(src, fw, fb, gb);
  k_final<<<2048,256,0,stream>>>(x, gb, out);
}

// Round 5
// 277.837 us; speedup vs baseline: 2.3369x; 1.2345x over previous
//
#include <hip/hip_runtime.h>
#include <math.h>

#define H 512
#define W 512
#define PLANE (H*W)       // 262144
#define PLANE4 (PLANE/4)  // 65536

// ---- per-input-channel 3x3 accumulate for a 2x2 quad, 4 output channels ----
// PL: scalar LDS plane, S: row stride, (YB,XB): window top-left (XB even),
// WB: uniform weight base (global), WS: co stride in floats.
#define ACC_CI(PL, S, YB, XB, WB, WS) { \
    float q[4][4]; \
    _Pragma("unroll") \
    for (int i4=0;i4<4;++i4){ \
      float2 aa=*(const float2*)&(PL)[((YB)+i4)*(S)+(XB)]; \
      float2 bb=*(const float2*)&(PL)[((YB)+i4)*(S)+(XB)+2]; \
      q[i4][0]=aa.x;q[i4][1]=aa.y;q[i4][2]=bb.x;q[i4][3]=bb.y; \
    } \
    _Pragma("unroll") \
    for (int co=0;co<4;++co){ \
      _Pragma("unroll") \
      for (int dy=0;dy<3;++dy){ \
        _Pragma("unroll") \
        for (int dx=0;dx<3;++dx){ \
          float wv=(WB)[co*(WS)+dy*3+dx]; \
          acc[co][0]+=q[dy][dx]*wv;   acc[co][1]+=q[dy][dx+1]*wv; \
          acc[co][2]+=q[dy+1][dx]*wv; acc[co][3]+=q[dy+1][dx+1]*wv; \
        } } } }

// single-output-channel variant (c7)
#define ACC_CI7(PL, S, YB, XB, WB) { \
    float q[4][4]; \
    _Pragma("unroll") \
    for (int i4=0;i4<4;++i4){ \
      float2 aa=*(const float2*)&(PL)[((YB)+i4)*(S)+(XB)]; \
      float2 bb=*(const float2*)&(PL)[((YB)+i4)*(S)+(XB)+2]; \
      q[i4][0]=aa.x;q[i4][1]=aa.y;q[i4][2]=bb.x;q[i4][3]=bb.y; \
    } \
    _Pragma("unroll") \
    for (int dy=0;dy<3;++dy){ \
      _Pragma("unroll") \
      for (int dx=0;dx<3;++dx){ \
        float wv=(WB)[dy*3+dx]; \
        s00+=q[dy][dx]*wv;   s01+=q[dy][dx+1]*wv; \
        s10+=q[dy+1][dx]*wv; s11+=q[dy+1][dx+1]*wv; \
      } } }

// ================= K1: v -> x1 -> x2 -> x3 =================
__launch_bounds__(512,4)
__global__ void k_conv_a(const float* __restrict__ xg,
    const float* __restrict__ c1w, const float* __restrict__ c1b,
    const float* __restrict__ c2w, const float* __restrict__ c2b,
    const float* __restrict__ c3w, const float* __restrict__ c3b,
    float* __restrict__ x1p, float* __restrict__ x2p, float* __restrict__ x3p)
{
  __shared__ float vb[38*38];
  __shared__ float p1[4][36*36];
  __shared__ float p2[4][34*34];
  int wg=blockIdx.x, b=wg>>8, t=wg&255, ty=t>>4, tx=t&15;
  int gy0=ty*32, gx0=tx*32, tid=threadIdx.x;
  const float* xp = xg + (size_t)b*3*PLANE;

  // stage v window, origin (gy0-3, gx0-3), zero outside image
  for (int i=tid;i<38*38;i+=512){
    int rr=i/38, cc=i-rr*38;
    int gy=gy0-3+rr, gx=gx0-3+cc;
    float val=0.f;
    if (((unsigned)gy<512u)&((unsigned)gx<512u)){
      int off=gy*W+gx;
      val=(xp[off]+xp[PLANE+off]+xp[2*PLANE+off])*(1.f/3.f);
    }
    vb[i]=val;
  }
  __syncthreads();

  // ---- c1: vb(38) -> p1(36) + x1 global, out origin (gy0-2, gx0-2)
  if (tid < 324){
    int qy=tid/18, qx=tid-qy*18;
    int y0=2*qy, x0=2*qx;
    float acc[4][4];
    #pragma unroll
    for (int co=0;co<4;++co){ float bv=c1b[co]; acc[co][0]=bv;acc[co][1]=bv;acc[co][2]=bv;acc[co][3]=bv; }
    ACC_CI(vb, 38, y0, x0, c1w, 9)
    bool okr0=(unsigned)(gy0-2+y0  )<512u;
    bool okr1=(unsigned)(gy0-2+y0+1)<512u;
    bool okc0=(unsigned)(gx0-2+x0  )<512u;
    bool okc1=(unsigned)(gx0-2+x0+1)<512u;
    #pragma unroll
    for (int co=0;co<4;++co){
      float v0=(okr0&okc0)?fmaxf(acc[co][0],0.f):0.f;
      float v1=(okr0&okc1)?fmaxf(acc[co][1],0.f):0.f;
      float v2=(okr1&okc0)?fmaxf(acc[co][2],0.f):0.f;
      float v3=(okr1&okc1)?fmaxf(acc[co][3],0.f):0.f;
      float2 lo={v0,v1}, hi={v2,v3};
      *(float2*)&p1[co][y0*36+x0]=lo;
      *(float2*)&p1[co][(y0+1)*36+x0]=hi;
      if (x0>=2 && x0<33){           // cols x0,x0+1 owned
        float* pl = x1p + ((size_t)(b*4+co))*PLANE;
        if (y0>=2 && y0<34)   *(float2*)&pl[(gy0-2+y0  )*512 + gx0-2+x0]=lo;
        if (y0+1>=2 && y0+1<34) *(float2*)&pl[(gy0-2+y0+1)*512 + gx0-2+x0]=hi;
      }
    }
  }
  __syncthreads();

  // ---- c2: p1(36) -> p2(34) + x2 global, out origin (gy0-1, gx0-1)
  if (tid < 289){
    int qy=tid/17, qx=tid-qy*17;
    int y0=2*qy, x0=2*qx;
    float acc[4][4];
    #pragma unroll
    for (int co=0;co<4;++co){ float bv=c2b[co]; acc[co][0]=bv;acc[co][1]=bv;acc[co][2]=bv;acc[co][3]=bv; }
    #pragma unroll
    for (int ci=0;ci<4;++ci){
      ACC_CI(p1[ci], 36, y0, x0, c2w + ci*9, 36)
    }
    bool okr0=(unsigned)(gy0-1+y0  )<512u;
    bool okr1=(unsigned)(gy0-1+y0+1)<512u;
    bool okc0=(unsigned)(gx0-1+x0  )<512u;
    bool okc1=(unsigned)(gx0-1+x0+1)<512u;
    bool own0=(unsigned)(y0-1)<32u;   // ly=y0 owned
    bool own1=(unsigned)(y0)<32u;     // ly=y0+1 owned
    int gyA=gy0-1+y0, gxA=gx0-1+x0;
    #pragma unroll
    for (int co=0;co<4;++co){
      float v0=(okr0&okc0)?fmaxf(acc[co][0],0.f):0.f;
      float v1=(okr0&okc1)?fmaxf(acc[co][1],0.f):0.f;
      float v2=(okr1&okc0)?fmaxf(acc[co][2],0.f):0.f;
      float v3=(okr1&okc1)?fmaxf(acc[co][3],0.f):0.f;
      *(float2*)&p2[co][y0*34+x0]=make_float2(v0,v1);
      *(float2*)&p2[co][(y0+1)*34+x0]=make_float2(v2,v3);
      float* pl = x2p + ((size_t)(b*4+co))*PLANE;
      if (x0==0){
        if (own0) pl[gyA*512+gxA+1]=v1;
        if (own1) pl[(gyA+1)*512+gxA+1]=v3;
      } else if (x0==32){
        if (own0) pl[gyA*512+gxA]=v0;
        if (own1) pl[(gyA+1)*512+gxA]=v2;
      } else {
        if (own0){ pl[gyA*512+gxA]=v0; pl[gyA*512+gxA+1]=v1; }
        if (own1){ pl[(gyA+1)*512+gxA]=v2; pl[(gyA+1)*512+gxA+1]=v3; }
      }
    }
  }
  __syncthreads();

  // ---- c3: p2(34) -> x3 global, out origin (gy0, gx0), all interior
  if (tid < 256){
    int qy=tid>>4, qx=tid&15;
    int y0=2*qy, x0=2*qx;
    float acc[4][4];
    #pragma unroll
    for (int co=0;co<4;++co){ float bv=c3b[co]; acc[co][0]=bv;acc[co][1]=bv;acc[co][2]=bv;acc[co][3]=bv; }
    #pragma unroll
    for (int ci=0;ci<4;++ci){
      ACC_CI(p2[ci], 34, y0, x0, c3w + ci*9, 36)
    }
    #pragma unroll
    for (int co=0;co<4;++co){
      float* pl = x3p + ((size_t)(b*4+co))*PLANE;
      *(float2*)&pl[(gy0+y0  )*512 + gx0+x0]=make_float2(fmaxf(acc[co][0],0.f),fmaxf(acc[co][1],0.f));
      *(float2*)&pl[(gy0+y0+1)*512 + gx0+x0]=make_float2(fmaxf(acc[co][2],0.f),fmaxf(acc[co][3],0.f));
    }
  }
}

// ================= K2: x3 -> x4 -> x5 =================
__launch_bounds__(512,4)
__global__ void k_conv_b(const float* __restrict__ x3p,
    const float* __restrict__ c4w, const float* __restrict__ c4b,
    const float* __restrict__ c5w, const float* __restrict__ c5b,
    float* __restrict__ x5p)
{
  __shared__ float p3[4][36*36];
  __shared__ float p4[4][34*34];
  int wg=blockIdx.x, b=wg>>8, t=wg&255, ty=t>>4, tx=t&15;
  int gy0=ty*32, gx0=tx*32, tid=threadIdx.x;

  // stage x3 window (origin gy0-2, gx0-2) as float2 units
  for (int i=tid; i<4*36*18; i+=512){
    int ch=i/(36*18); int rem=i-ch*(36*18);
    int rr=rem/18, cc=rem-rr*18;
    int gy=gy0-2+rr, gx=gx0-2+2*cc;
    float2 v=make_float2(0.f,0.f);
    if (((unsigned)gy<512u)&((unsigned)gx<512u))
      v = *(const float2*)&x3p[((size_t)(b*4+ch))*PLANE + gy*512+gx];
    *(float2*)&p3[ch][rr*36+2*cc]=v;
  }
  __syncthreads();

  // ---- c4: p3(36) -> p4(34), out origin (gy0-1, gx0-1), LDS only
  if (tid < 289){
    int qy=tid/17, qx=tid-qy*17;
    int y0=2*qy, x0=2*qx;
    float acc[4][4];
    #pragma unroll
    for (int co=0;co<4;++co){ float bv=c4b[co]; acc[co][0]=bv;acc[co][1]=bv;acc[co][2]=bv;acc[co][3]=bv; }
    #pragma unroll
    for (int ci=0;ci<4;++ci){
      ACC_CI(p3[ci], 36, y0, x0, c4w + ci*9, 36)
    }
    bool okr0=(unsigned)(gy0-1+y0  )<512u;
    bool okr1=(unsigned)(gy0-1+y0+1)<512u;
    bool okc0=(unsigned)(gx0-1+x0  )<512u;
    bool okc1=(unsigned)(gx0-1+x0+1)<512u;
    #pragma unroll
    for (int co=0;co<4;++co){
      float v0=(okr0&okc0)?fmaxf(acc[co][0],0.f):0.f;
      float v1=(okr0&okc1)?fmaxf(acc[co][1],0.f):0.f;
      float v2=(okr1&okc0)?fmaxf(acc[co][2],0.f):0.f;
      float v3=(okr1&okc1)?fmaxf(acc[co][3],0.f):0.f;
      *(float2*)&p4[co][y0*34+x0]=make_float2(v0,v1);
      *(float2*)&p4[co][(y0+1)*34+x0]=make_float2(v2,v3);
    }
  }
  __syncthreads();

  // ---- c5: concat(p3@+1, p4) -> x5 global, out origin (gy0, gx0)
  if (tid < 256){
    int qy=tid>>4, qx=tid&15;
    int y0=2*qy, x0=2*qx;
    float acc[4][4];
    #pragma unroll
    for (int co=0;co<4;++co){ float bv=c5b[co]; acc[co][0]=bv;acc[co][1]=bv;acc[co][2]=bv;acc[co][3]=bv; }
    #pragma unroll
    for (int ci=0;ci<4;++ci){
      ACC_CI(p3[ci], 36, y0+1, x0+1, c5w + ci*9, 72)
    }
    #pragma unroll
    for (int ci=0;ci<4;++ci){
      ACC_CI(p4[ci], 34, y0, x0, c5w + (4+ci)*9, 72)
    }
    #pragma unroll
    for (int co=0;co<4;++co){
      float* pl = x5p + ((size_t)(b*4+co))*PLANE;
      *(float2*)&pl[(gy0+y0  )*512 + gx0+x0]=make_float2(fmaxf(acc[co][0],0.f),fmaxf(acc[co][1],0.f));
      *(float2*)&pl[(gy0+y0+1)*512 + gx0+x0]=make_float2(fmaxf(acc[co][2],0.f),fmaxf(acc[co][3],0.f));
    }
  }
}

// ================= K3: x2,x5 -> x6 ; x1,x6 -> v_r =================
__launch_bounds__(512,4)
__global__ void k_conv_c(const float* __restrict__ x1p,
    const float* __restrict__ x2p, const float* __restrict__ x5p,
    const float* __restrict__ c6w, const float* __restrict__ c6b,
    const float* __restrict__ c7w, const float* __restrict__ c7b,
    float* __restrict__ vr)
{
  __shared__ float p2s[4][36*36];
  __shared__ float p5[4][36*36];
  __shared__ float p1s[4][34*34];
  __shared__ float p6[4][34*34];
  int wg=blockIdx.x, b=wg>>8, t=wg&255, ty=t>>4, tx=t&15;
  int gy0=ty*32, gx0=tx*32, tid=threadIdx.x;

  // stage x2, x5 windows (origin gy0-2, gx0-2), float2
  for (int i=tid; i<8*36*18; i+=512){
    int pi=i/(4*36*18);              // 0 -> x2, 1 -> x5
    int rem0=i-pi*(4*36*18);
    int ch=rem0/(36*18); int rem=rem0-ch*(36*18);
    int rr=rem/18, cc=rem-rr*18;
    int gy=gy0-2+rr, gx=gx0-2+2*cc;
    float2 v=make_float2(0.f,0.f);
    const float* sp = (pi==0 ? x2p : x5p) + ((size_t)(b*4+ch))*PLANE;
    if (((unsigned)gy<512u)&((unsigned)gx<512u))
      v = *(const float2*)&sp[gy*512+gx];
    if (pi==0) *(float2*)&p2s[ch][rr*36+2*cc]=v;
    else       *(float2*)&p5 [ch][rr*36+2*cc]=v;
  }
  // stage x1 window (origin gy0-1, gx0-1), scalar (odd offset)
  for (int i=tid; i<4*34*34; i+=512){
    int ch=i/1156; int rem=i-ch*1156;
    int rr=rem/34, cc=rem-rr*34;
    int gy=gy0-1+rr, gx=gx0-1+cc;
    float v=0.f;
    if (((unsigned)gy<512u)&((unsigned)gx<512u))
      v = x1p[((size_t)(b*4+ch))*PLANE + gy*512+gx];
    p1s[ch][rem]=v;
  }
  __syncthreads();

  // ---- c6: concat(p2s, p5) -> p6(34), out origin (gy0-1, gx0-1), LDS only
  if (tid < 289){
    int qy=tid/17, qx=tid-qy*17;
    int y0=2*qy, x0=2*qx;
    float acc[4][4];
    #pragma unroll
    for (int co=0;co<4;++co){ float bv=c6b[co]; acc[co][0]=bv;acc[co][1]=bv;acc[co][2]=bv;acc[co][3]=bv; }
    #pragma unroll
    for (int ci=0;ci<4;++ci){
      ACC_CI(p2s[ci], 36, y0, x0, c6w + ci*9, 72)
    }
    #pragma unroll
    for (int ci=0;ci<4;++ci){
      ACC_CI(p5[ci], 36, y0, x0, c6w + (4+ci)*9, 72)
    }
    bool okr0=(unsigned)(gy0-1+y0  )<512u;
    bool okr1=(unsigned)(gy0-1+y0+1)<512u;
    bool okc0=(unsigned)(gx0-1+x0  )<512u;
    bool okc1=(unsigned)(gx0-1+x0+1)<512u;
    #pragma unroll
    for (int co=0;co<4;++co){
      float v0=(okr0&okc0)?fmaxf(acc[co][0],0.f):0.f;
      float v1=(okr0&okc1)?fmaxf(acc[co][1],0.f):0.f;
      float v2=(okr1&okc0)?fmaxf(acc[co][2],0.f):0.f;
      float v3=(okr1&okc1)?fmaxf(acc[co][3],0.f):0.f;
      *(float2*)&p6[co][y0*34+x0]=make_float2(v0,v1);
      *(float2*)&p6[co][(y0+1)*34+x0]=make_float2(v2,v3);
    }
  }
  __syncthreads();

  // ---- c7: concat(p1s, p6) -> sigmoid -> v_r, out origin (gy0, gx0)
  if (tid < 256){
    int qy=tid>>4, qx=tid&15;
    int y0=2*qy, x0=2*qx;
    float bv=c7b[0];
    float s00=bv, s01=bv, s10=bv, s11=bv;
    #pragma unroll
    for (int ci=0;ci<4;++ci){
      ACC_CI7(p1s[ci], 34, y0, x0, c7w + ci*9)
    }
    #pragma unroll
    for (int ci=0;ci<4;++ci){
      ACC_CI7(p6[ci], 34, y0, x0, c7w + (4+ci)*9)
    }
    float* vo = vr + (size_t)b*PLANE;
    *(float2*)&vo[(gy0+y0  )*512 + gx0+x0] =
        make_float2(1.f/(1.f+expf(-s00)), 1.f/(1.f+expf(-s01)));
    *(float2*)&vo[(gy0+y0+1)*512 + gx0+x0] =
        make_float2(1.f/(1.f+expf(-s10)), 1.f/(1.f+expf(-s11)));
  }
}

// ---------------- subsample + m-conv(stride2) + leaky + instance norm -> src(S,B,E) ----------------
__launch_bounds__(256)
__global__ void k_mnorm(const float* __restrict__ xg, const float* __restrict__ mw,
                        const float* __restrict__ mb, const float* __restrict__ ing,
                        const float* __restrict__ inb, float* __restrict__ src){
  int bc = blockIdx.x;           // 128 = b*16+c
  int b = bc >> 4, c = bc & 15;
  int tid = threadIdx.x;         // 256 = out pixel (i*16+j)
  int i = tid >> 4, j = tid & 15;
  const float* xp = xg + (size_t)b*3*PLANE;
  float s = mb[c];
  #pragma unroll
  for (int dy=0; dy<3; ++dy){
    int ii = 2*i - 1 + dy;
    if ((unsigned)ii >= 32u) continue;
    #pragma unroll
    for (int dx=0; dx<3; ++dx){
      int jj = 2*j - 1 + dx;
      if ((unsigned)jj >= 32u) continue;
      int off = (ii*16)*W + jj*16;
      float vv = (xp[off] + xp[PLANE+off] + xp[2*PLANE+off]) * (1.f/3.f);
      s += vv * mw[c*9 + dy*3 + dx];
    }
  }
  float h = (s >= 0.f) ? s : 0.2f*s;
  __shared__ float red[256];
  red[tid] = h; __syncthreads();
  for (int off=128; off; off>>=1){ if (tid<off) red[tid]+=red[tid+off]; __syncthreads(); }
  float mu = red[0] * (1.f/256.f);
  __syncthreads();
  float d = h - mu;
  red[tid] = d*d; __syncthreads();
  for (int off=128; off; off>>=1){ if (tid<off) red[tid]+=red[tid+off]; __syncthreads(); }
  float var = red[0] * (1.f/256.f);
  float yv = d * rsqrtf(var + 1e-5f) * ing[c] + inb[c];
  src[(size_t)tid*128 + b*16 + c] = yv;   // src[s][b][e], s=tid
}

// ---------------- qkv projection ----------------
__launch_bounds__(256)
__global__ void k_qkv(const float* __restrict__ src, const float* __restrict__ aw,
                      const float* __restrict__ ab, float* __restrict__ qkv){
  int id = blockIdx.x*256 + threadIdx.x;  // 2048*48 = 98304
  int tok = id / 48, o = id % 48;
  const float* sr = src + tok*16;
  float s = ab[o];
  #pragma unroll
  for (int e=0; e<16; ++e) s += sr[e]*aw[o*16+e];
  qkv[tok*48+o] = s;
}

// ---------------- attention (per b,h block; head dim = 2) ----------------
__launch_bounds__(256)
__global__ void k_attn(const float* __restrict__ qkv, float* __restrict__ obuf){
  int b = blockIdx.x >> 3, hh = blockIdx.x & 7;  // 64 blocks
  int t = threadIdx.x;                           // s index
  __shared__ float kk0[256], kk1[256], vv0[256], vv1[256];
  int tok = t*8 + b;
  const float* qr = qkv + tok*48;
  kk0[t] = qr[16 + hh*2]; kk1[t] = qr[16 + hh*2 + 1];
  vv0[t] = qr[32 + hh*2]; vv1[t] = qr[32 + hh*2 + 1];
  float q0 = qr[hh*2], q1 = qr[hh*2 + 1];
  __syncthreads();
  const float sc = 0.70710678118654752f;  // 1/sqrt(2)
  float m = -1e30f;
  for (int u=0; u<256; ++u){
    float s = (q0*kk0[u] + q1*kk1[u]) * sc;
    m = fmaxf(m, s);
  }
  float l = 0.f, a0 = 0.f, a1 = 0.f;
  for (int u=0; u<256; ++u){
    float s = (q0*kk0[u] + q1*kk1[u]) * sc;
    float p = expf(s - m);
    l += p; a0 += p*vv0[u]; a1 += p*vv1[u];
  }
  float inv = 1.f/l;
  obuf[tok*16 + hh*2]     = a0*inv;
  obuf[tok*16 + hh*2 + 1] = a1*inv;
}

// ---------------- out-proj + residual + layernorm1 (in-place on src) ----------------
__launch_bounds__(256)
__global__ void k_oproj_ln(const float* __restrict__ obuf, const float* __restrict__ ow,
                           const float* __restrict__ obias, const float* __restrict__ g,
                           const float* __restrict__ bb, float* __restrict__ src){
  int tok = blockIdx.x*256 + threadIdx.x;  // 2048
  const float* orow = obuf + tok*16;
  float xv[16];
  #pragma unroll
  for (int e=0; e<16; ++e){
    float s = obias[e];
    #pragma unroll
    for (int f=0; f<16; ++f) s += orow[f]*ow[e*16+f];
    xv[e] = src[tok*16+e] + s;
  }
  float mu = 0.f;
  #pragma unroll
  for (int e=0; e<16; ++e) mu += xv[e];
  mu *= (1.f/16.f);
  float var = 0.f;
  #pragma unroll
  for (int e=0; e<16; ++e){ float d = xv[e]-mu; var += d*d; }
  var *= (1.f/16.f);
  float rs = rsqrtf(var + 1e-5f);
  #pragma unroll
  for (int e=0; e<16; ++e) src[tok*16+e] = (xv[e]-mu)*rs*g[e] + bb[e];
}

// ---------------- FFN + residual + layernorm2 (in-place on src) ----------------
__launch_bounds__(64)
__global__ void k_ffn_ln(float* __restrict__ src, const float* __restrict__ w1,
                         const float* __restrict__ b1, const float* __restrict__ w2,
                         const float* __restrict__ b2, const float* __restrict__ g,
                         const float* __restrict__ bb){
  int tok = blockIdx.x;     // 2048
  int tid = threadIdx.x;    // 64
  __shared__ float srow[16], h1[128], xr[16];
  if (tid < 16) srow[tid] = src[tok*16+tid];
  __syncthreads();
  for (int i = tid; i < 128; i += 64){
    float s = b1[i];
    #pragma unroll
    for (int e=0; e<16; ++e) s += srow[e]*w1[i*16+e];
    h1[i] = fmaxf(s, 0.f);
  }
  __syncthreads();
  if (tid < 16){
    float s = b2[tid];
    for (int j=0; j<128; ++j) s += h1[j]*w2[tid*128+j];
    xr[tid] = srow[tid] + s;
  }
  __syncthreads();
  if (tid < 16){
    float mu = 0.f;
    #pragma unroll
    for (int e=0; e<16; ++e) mu += xr[e];
    mu *= (1.f/16.f);
    float var = 0.f;
    #pragma unroll
    for (int e=0; e<16; ++e){ float d = xr[e]-mu; var += d*d; }
    var *= (1.f/16.f);
    src[tok*16+tid] = (xr[tid]-mu)*rsqrtf(var+1e-5f)*g[tid] + bb[tid];
  }
}

// ---------------- final 16x16 valid conv -> level -> g/bcf scalars ----------------
__launch_bounds__(256)
__global__ void k_level(const float* __restrict__ src, const float* __restrict__ fw,
                        const float* __restrict__ fb, float* __restrict__ gb){
  int b = blockIdx.x >> 1, k = blockIdx.x & 1;  // 16 blocks
  int tid = threadIdx.x;                        // s pixel
  float s = 0.f;
  #pragma unroll
  for (int c=0; c<16; ++c)
    s += src[(size_t)tid*128 + b*16 + c] * fw[(k*16+c)*256 + tid];
  __shared__ float red[256];
  red[tid] = s; __syncthreads();
  for (int off=128; off; off>>=1){ if (tid<off) red[tid]+=red[tid+off]; __syncthreads(); }
  if (tid == 0){
    float lev = 1.f/(1.f + expf(-(red[0] + fb[k])));
    gb[b*2+k] = (k==0) ? (0.1f*lev + 0.2f) : (0.04f*lev + 0.06f);
  }
}

// ---------------- final elementwise: enhance + t ----------------
__launch_bounds__(256)
__global__ void k_final(const float* __restrict__ x, const float* __restrict__ gb,
                        float* __restrict__ out){
  int id = blockIdx.x*256 + threadIdx.x;  // 524288
  int b = id >> 16, p = id & 65535;
  const float4* xr = (const float4*)(x + (size_t)(b*3+0)*PLANE);
  const float4* xg = (const float4*)(x + (size_t)(b*3+1)*PLANE);
  const float4* xb = (const float4*)(x + (size_t)(b*3+2)*PLANE);
  const float4* vrp = (const float4*)(out + 6291456 + (size_t)b*PLANE);
  float4 R = xr[p], G = xg[p], Bl = xb[p], VR = vrp[p];
  float gg = gb[b*2+0], bc = gb[b*2+1];
  float lg = log2f(gg);
  float4 er, eg, eb, tr, tg, tb;
#define COMP(SUF, RF, GF, BF, VRF) {            \
    float vv = (RF + GF + BF)/3.f;              \
    float v0 = fminf(fmaxf(vv, 1e-6f), 0.999999f); \
    float r0 = exp2f(VRF * lg);                 \
    float ev0 = exp2f(r0 * log2f(v0));          \
    float d = bc - vv;                          \
    float L = 400.f*d*d*d;                      \
    L = (L < 1e-5f) ? 1e-6f : L;                \
    float fac = (ev0 - L) / (vv + 1e-6f);       \
    er.SUF = RF*fac; eg.SUF = GF*fac; eb.SUF = BF*fac; \
    bool z = vv > 0.04f;                        \
    tr.SUF = z ? 0.f : er.SUF; tg.SUF = z ? 0.f : eg.SUF; tb.SUF = z ? 0.f : eb.SUF; }
  COMP(x, R.x, G.x, Bl.x, VR.x)
  COMP(y, R.y, G.y, Bl.y, VR.y)
  COMP(z, R.z, G.z, Bl.z, VR.z)
  COMP(w, R.w, G.w, Bl.w, VR.w)
#undef COMP
  float4* oe = (float4*)out;
  float4* ot = (float4*)(out + 8388608);
  oe[(size_t)(b*3+0)*PLANE4 + p] = er;
  oe[(size_t)(b*3+1)*PLANE4 + p] = eg;
  oe[(size_t)(b*3+2)*PLANE4 + p] = eb;
  ot[(size_t)(b*3+0)*PLANE4 + p] = tr;
  ot[(size_t)(b*3+1)*PLANE4 + p] = tg;
  ot[(size_t)(b*3+2)*PLANE4 + p] = tb;
}

extern "C" void kernel_launch(void* const* d_in, const int* in_sizes, int n_in,
                              void* d_out, int out_size, void* d_ws, size_t ws_size,
                              hipStream_t stream) {
  const float* x    = (const float*)d_in[0];
  const float* c1w  = (const float*)d_in[1];  const float* c1b = (const float*)d_in[2];
  const float* c2w  = (const float*)d_in[3];  const float* c2b = (const float*)d_in[4];
  const float* c3w  = (const float*)d_in[5];  const float* c3b = (const float*)d_in[6];
  const float* c4w  = (const float*)d_in[7];  const float* c4b = (const float*)d_in[8];
  const float* c5w  = (const float*)d_in[9];  const float* c5b = (const float*)d_in[10];
  const float* c6w  = (const float*)d_in[11]; const float* c6b = (const float*)d_in[12];
  const float* c7w  = (const float*)d_in[13]; const float* c7b = (const float*)d_in[14];
  const float* mw   = (const float*)d_in[15]; const float* mb  = (const float*)d_in[16];
  const float* ing  = (const float*)d_in[17]; const float* inb = (const float*)d_in[18];
  const float* aw   = (const float*)d_in[19]; const float* ab  = (const float*)d_in[20];
  const float* ow   = (const float*)d_in[21]; const float* ob  = (const float*)d_in[22];
  const float* l1w  = (const float*)d_in[23]; const float* l1b = (const float*)d_in[24];
  const float* l2w  = (const float*)d_in[25]; const float* l2b = (const float*)d_in[26];
  const float* n1g  = (const float*)d_in[27]; const float* n1b = (const float*)d_in[28];
  const float* n2g  = (const float*)d_in[29]; const float* n2b = (const float*)d_in[30];
  const float* fw   = (const float*)d_in[31]; const float* fb  = (const float*)d_in[32];

  float* wsf = (float*)d_ws;
  float* x1p = wsf;                  // 8*4*PLANE = 8.39M floats each
  float* x2p = x1p + 8*4*PLANE;
  float* x3p = x2p + 8*4*PLANE;
  float* x5p = x3p + 8*4*PLANE;
  float* src  = x5p + 8*4*PLANE;     // 32,768
  float* qkv  = src + 32768;         // 98,304
  float* obuf = qkv + 98304;         // 32,768
  float* gb   = obuf+ 32768;         // 16
  float* out  = (float*)d_out;
  float* vr   = out + 6291456;       // v_r output region

  k_conv_a<<<2048,512,0,stream>>>(x, c1w,c1b, c2w,c2b, c3w,c3b, x1p, x2p, x3p);
  k_conv_b<<<2048,512,0,stream>>>(x3p, c4w,c4b, c5w,c5b, x5p);
  k_conv_c<<<2048,512,0,stream>>>(x1p, x2p, x5p, c6w,c6b, c7w,c7b, vr);
  k_mnorm<<<128,256,0,stream>>>(x, mw, mb, ing, inb, src);
  k_qkv<<<384,256,0,stream>>>(src, aw, ab, qkv);
  k_attn<<<64,256,0,stream>>>(qkv, obuf);
  k_oproj_ln<<<8,256,0,stream>>>(obuf, ow, ob, n1g, n1b, src);
  k_ffn_ln<<<2048,64,0,stream>>>(src, l1w, l1b, l2w, l2b, n2g, n2b);
  k_level<<<16,256,0,stream>>>(src, fw, fb, gb);
  k_final<<<2048,256,0,stream>>>(x, gb, out);
}